// Round 2
// baseline (2428.087 us; speedup 1.0000x reference)
//
#include <hip/hip_runtime.h>
#include <hip/hip_bf16.h>
#include <stdint.h>

// ---------------------------------------------------------------------------
// LinearSelfAttention (Performer-style) on gfx950.
//   V     = x @ W_v                         (f16 MFMA, A cast f32->f16 in-staging)
//   P/S   = pos/slopes @ W_pf               (split-f16: virtual K=3072 [hi|lo|hi]
//                                            built in-staging vs B=[hi;hi;lo])
//   q',k' = fourier features (fp32 VALU dd = qp@projT, hw sin/cos), norm folded
//   kvT   = sum_l v[l][d] k'[l][m]          (f16 MFMA, LDS transpose, split-K atomics)
//   z     = q'' @ kvT                       (batched f16 MFMA)
//   out   = z @ W_o                         (f16 MFMA, f32 out)
// Fourier/kv/z stages chunked over b to keep workspace ~184 MB (R1 core dump
// was workspace overflow at 553 MB).
// ---------------------------------------------------------------------------

typedef _Float16 hx8 __attribute__((ext_vector_type(8)));
typedef _Float16 hx4 __attribute__((ext_vector_type(4)));
typedef float    fx4 __attribute__((ext_vector_type(4)));

#define H_   16
#define D_   64
#define L_   4096
#define B_   4
#define BL_  16384
#define KV_SPLIT 8

// ---------------- prep kernels ----------------
// W [1024][1024] f32 -> WT [1024][1024] f16 (WT[n][k] = W[k][n])
__global__ __launch_bounds__(256) void wt_k(const float* __restrict__ W,
                                            _Float16* __restrict__ WT) {
  __shared__ float tile[64][65];
  int t = threadIdx.x; int c = t & 63; int r0 = t >> 6;
  int bx = blockIdx.x * 64, by = blockIdx.y * 64;
  for (int r = r0; r < 64; r += 4) tile[r][c] = W[(long)(by + r) * 1024 + bx + c];
  __syncthreads();
  for (int r = r0; r < 64; r += 4)
    WT[(long)(bx + r) * 1024 + by + c] = (_Float16)tile[c][r];
}

// W_pf -> WT3 [1024][3072] f16 sections: [hi ; hi ; lo] (transposed)
__global__ __launch_bounds__(256) void wpf3_k(const float* __restrict__ W,
                                              _Float16* __restrict__ WT3) {
  __shared__ float tile[64][65];
  int t = threadIdx.x; int c = t & 63; int r0 = t >> 6;
  int bx = blockIdx.x * 64, by = blockIdx.y * 64;
  for (int r = r0; r < 64; r += 4) tile[r][c] = W[(long)(by + r) * 1024 + bx + c];
  __syncthreads();
  for (int r = r0; r < 64; r += 4) {
    float x = tile[c][r];
    _Float16 hi = (_Float16)x;
    _Float16 lo = (_Float16)(x - (float)hi);
    long base = (long)(bx + r) * 3072 + by + c;
    WT3[base] = hi; WT3[base + 1024] = hi; WT3[base + 2048] = lo;
  }
}

__global__ __launch_bounds__(256) void zero_k(float* __restrict__ p, int n4) {
  int i = blockIdx.x * 256 + threadIdx.x;
  int stride = gridDim.x * 256;
  fx4 z = {0.f, 0.f, 0.f, 0.f};
  for (; i < n4; i += stride) ((fx4*)p)[i] = z;
}

__global__ __launch_bounds__(256) void cast_out_f16_k(const float* __restrict__ in,
                                                      _Float16* __restrict__ out, int n) {
  int i = blockIdx.x * 256 + threadIdx.x;
  int stride = gridDim.x * 256;
  for (; i < n; i += stride) out[i] = (_Float16)in[i];
}

// ---------------- generic f16 MFMA GEMM:  C[M][N] = A[M][K] @ BT[N][K]^T ----
// BK=64, 256 threads, 4 waves in 2x2; XOR-swizzled LDS (conflict-free b128).
// AMODE: 0 = A is f16; 1 = A is f32 (cast during staging, lda in f32 elems);
//        2 = A is f32 [R][1024], virtual K=3072 as [hi|lo|hi] split-f16.
// Batched via blockIdx.z decomposed as (z>>4, z&15) with per-component strides.
template<int BM, int BN, int AMODE, typename OUT_T>
__global__ __launch_bounds__(256) void gemm_bt_k(
    const void* __restrict__ Av, const _Float16* __restrict__ BT,
    OUT_T* __restrict__ C, int K, int lda, int ldb, int ldc,
    long sAb, long sAh, long sBb, long sBh, long sCb, long sCh)
{
  __shared__ __align__(16) _Float16 sA[BM * 64];
  __shared__ __align__(16) _Float16 sB[BN * 64];
  const int t = threadIdx.x;
  const int lane = t & 63;
  const int w = t >> 6;
  const int wm = w >> 1, wn = w & 1;
  const int bx = blockIdx.x, by = blockIdx.y, bz = blockIdx.z;
  long aoff = (long)(bz >> 4) * sAb + (long)(bz & 15) * sAh;
  BT += (long)(bz >> 4) * sBb + (long)(bz & 15) * sBh;
  C  += (long)(bz >> 4) * sCb + (long)(bz & 15) * sCh;
  const _Float16* A16 = (const _Float16*)Av + aoff;
  const float*    A32 = (const float*)Av + aoff;
  constexpr int WTM = BM / 32, WTN = BN / 32;
  fx4 acc[WTM][WTN];
#pragma unroll
  for (int i = 0; i < WTM; ++i)
#pragma unroll
    for (int j = 0; j < WTN; ++j) acc[i][j] = (fx4){0.f, 0.f, 0.f, 0.f};

  for (int k0 = 0; k0 < K; k0 += 64) {
    __syncthreads();
    // ---- stage A tile [BM x 64] ----
    if constexpr (AMODE == 0) {
#pragma unroll
      for (int i = 0; i < BM / 32; ++i) {
        int s = i * 256 + t; int row = s >> 3; int kc = (s & 7) ^ (row & 7);
        *(uint4*)&sA[s * 8] =
            *(const uint4*)&A16[(long)(by * BM + row) * lda + k0 + kc * 8];
      }
    } else {
      int mode, cs;
      if constexpr (AMODE == 2) { mode = k0 >> 10; cs = k0 & 1023; }
      else                      { mode = 0;        cs = k0;        }
#pragma unroll
      for (int i = 0; i < BM / 32; ++i) {
        int s = i * 256 + t; int row = s >> 3; int kc = (s & 7) ^ (row & 7);
        const float* src = A32 + (long)(by * BM + row) * lda + cs + kc * 8;
        fx4 v0 = *(const fx4*)src;
        fx4 v1 = *(const fx4*)(src + 4);
        hx8 hv;
        if (mode != 1) {
#pragma unroll
          for (int e = 0; e < 4; ++e) { hv[e] = (_Float16)v0[e]; hv[4 + e] = (_Float16)v1[e]; }
        } else {
#pragma unroll
          for (int e = 0; e < 4; ++e) {
            _Float16 h0 = (_Float16)v0[e]; hv[e]     = (_Float16)(v0[e] - (float)h0);
            _Float16 h1 = (_Float16)v1[e]; hv[4 + e] = (_Float16)(v1[e] - (float)h1);
          }
        }
        *(hx8*)&sA[s * 8] = hv;
      }
    }
    // ---- stage B tile [BN x 64] ----
#pragma unroll
    for (int i = 0; i < BN / 32; ++i) {
      int s = i * 256 + t; int row = s >> 3; int kc = (s & 7) ^ (row & 7);
      *(uint4*)&sB[s * 8] =
          *(const uint4*)&BT[(long)(bx * BN + row) * ldb + k0 + kc * 8];
    }
    __syncthreads();
#pragma unroll
    for (int kk = 0; kk < 64; kk += 32) {
      hx8 af[WTM], bf[WTN];
      int kcb = (kk >> 3) + (lane >> 4);
#pragma unroll
      for (int i = 0; i < WTM; ++i) {
        int r = wm * (BM / 2) + i * 16 + (lane & 15);
        af[i] = *(const hx8*)&sA[(r * 8 + (kcb ^ (r & 7))) * 8];
      }
#pragma unroll
      for (int j = 0; j < WTN; ++j) {
        int r = wn * (BN / 2) + j * 16 + (lane & 15);
        bf[j] = *(const hx8*)&sB[(r * 8 + (kcb ^ (r & 7))) * 8];
      }
#pragma unroll
      for (int i = 0; i < WTM; ++i)
#pragma unroll
        for (int j = 0; j < WTN; ++j)
          acc[i][j] = __builtin_amdgcn_mfma_f32_16x16x32_f16(af[i], bf[j], acc[i][j], 0, 0, 0);
    }
  }
#pragma unroll
  for (int i = 0; i < WTM; ++i) {
#pragma unroll
    for (int j = 0; j < WTN; ++j) {
      int rowb = by * BM + wm * (BM / 2) + i * 16 + ((lane >> 4) << 2);
      int col  = bx * BN + wn * (BN / 2) + j * 16 + (lane & 15);
#pragma unroll
      for (int r = 0; r < 4; ++r)
        C[(long)(rowb + r) * ldc + col] = (OUT_T)acc[i][j][r];
    }
  }
}

// ---------------- fourier feature kernel (per-b chunk) ----------------
// One block = 2 (l,h) pairs; 2 waves per pair (each wave does 64 of 128 m's).
// P,S are this b's [4096][1024] f32; Qp,Kp are this b's [H][L][256] f16.
__global__ __launch_bounds__(256) void kf_k(
    const float* __restrict__ P, const float* __restrict__ S,
    const float* __restrict__ proj, const float* __restrict__ scale_p,
    const float* __restrict__ offs_p,
    _Float16* __restrict__ Qp, _Float16* __restrict__ Kp)
{
  __shared__ __align__(16) float sQP[2][64];
  __shared__ __align__(16) float sKP[2][64];
  __shared__ float sNorm[2];
  const int t = threadIdx.x, lane = t & 63, w = t >> 6;
  const int pair = w >> 1, mhalf = w & 1;
  const int pairIdx = blockIdx.x * 2 + pair;       // = l*16 + h
  const int h = pairIdx & 15;
  const int l = pairIdx >> 4;
  const float cnorm = 0.35355339059327373f;        // 1/64^0.25
  long off = (long)pairIdx * 64 + lane;            // d = lane
  float pv = P[off], sv = S[off];
  float scale = scale_p[h], offs = offs_p[h];
  float qp = cnorm * scale * pv;
  float kp = qp + cnorm * offs * scale * sv;
  if (mhalf == 0) {
    sQP[pair][lane] = qp; sKP[pair][lane] = kp;
    float ss = sv * sv;
#pragma unroll
    for (int o = 32; o > 0; o >>= 1) ss += __shfl_down(ss, o, 64);
    if (lane == 0) sNorm[pair] = sqrtf(ss) * (1.0f / 4096.0f);
  }
  __syncthreads();
  const int m = mhalf * 64 + lane;
  float pr[64];
  const fx4* pj = (const fx4*)(proj + m * 64);
#pragma unroll
  for (int i = 0; i < 16; ++i) {
    fx4 v = pj[i];
    pr[4*i] = v[0]; pr[4*i+1] = v[1]; pr[4*i+2] = v[2]; pr[4*i+3] = v[3];
  }
  float ddq = 0.f, ddk = 0.f;
  const fx4* q4 = (const fx4*)sQP[pair];
  const fx4* k4 = (const fx4*)sKP[pair];
#pragma unroll
  for (int i = 0; i < 16; ++i) {
    fx4 qv = q4[i], kv = k4[i];
    ddq += qv[0]*pr[4*i+0]; ddk += kv[0]*pr[4*i+0];
    ddq += qv[1]*pr[4*i+1]; ddk += kv[1]*pr[4*i+1];
    ddq += qv[2]*pr[4*i+2]; ddk += kv[2]*pr[4*i+2];
    ddq += qv[3]*pr[4*i+3]; ddk += kv[3]*pr[4*i+3];
  }
  const float inv2pi = 0.15915494309189535f;
  const float ratio  = 0.08838834764831845f;       // 1/sqrt(128)
  float rq = ddq * inv2pi; rq -= floorf(rq);       // revolutions in [0,1)
  float rk = ddk * inv2pi; rk -= floorf(rk);
  float sq = __builtin_amdgcn_sinf(rq), cq = __builtin_amdgcn_cosf(rq);
  float sk = __builtin_amdgcn_sinf(rk), ck = __builtin_amdgcn_cosf(rk);
  float rn = ratio * sNorm[pair];                  // fold norm_factor into q'
  long ob = ((long)h * 4096 + l) * 256;            // layout [H][L][256]
  Qp[ob + m]       = (_Float16)(rn * sq);
  Qp[ob + 128 + m] = (_Float16)(rn * cq);
  Kp[ob + m]       = (_Float16)(ratio * sk);
  Kp[ob + 128 + m] = (_Float16)(ratio * ck);
}

// ---------------- kv kernel (per-b): kvT[d][m] = sum_l v[l][d] * k'[l][m] ---
// Kp: this b's [H][L][256]; Vhb: this b's [L][1024]; kvacc: this b's [H][64][256].
__global__ __launch_bounds__(256) void kv_k(const _Float16* __restrict__ Kp,
                                            const _Float16* __restrict__ Vhb,
                                            float* __restrict__ kvacc)
{
  __shared__ __align__(16) _Float16 sK[256 * 72];   // [m][l] stride 72
  __shared__ __align__(16) _Float16 sV[64 * 72];    // [d][l]
  const int t = threadIdx.x, lane = t & 63, w = t >> 6;
  const int h = blockIdx.x;
  const int l0 = blockIdx.y * (L_ / KV_SPLIT);
  fx4 acc[4][4];
#pragma unroll
  for (int i = 0; i < 4; ++i)
#pragma unroll
    for (int j = 0; j < 4; ++j) acc[i][j] = (fx4){0.f, 0.f, 0.f, 0.f};
  const _Float16* Kbase = Kp + (long)h * L_ * 256;
  for (int kt = 0; kt < L_ / KV_SPLIT; kt += 64) {
    __syncthreads();
#pragma unroll
    for (int i = 0; i < 8; ++i) {               // k' tile: 64 l x 256 m, transpose
      int mc = w + 4 * i;                       // 0..31 (wave-uniform)
      hx8 vv = *(const hx8*)&Kbase[(long)(l0 + kt + lane) * 256 + mc * 8];
#pragma unroll
      for (int e = 0; e < 8; ++e) sK[(mc * 8 + e) * 72 + lane] = vv[e];
    }
#pragma unroll
    for (int i = 0; i < 2; ++i) {               // v tile: 64 l x 64 d, transpose
      int dc = w + 4 * i;                       // 0..7
      hx8 vv = *(const hx8*)&Vhb[(long)(l0 + kt + lane) * 1024 + h * 64 + dc * 8];
#pragma unroll
      for (int e = 0; e < 8; ++e) sV[(dc * 8 + e) * 72 + lane] = vv[e];
    }
    __syncthreads();
#pragma unroll
    for (int kk = 0; kk < 64; kk += 32) {
      hx8 af[4], bf[4];
      int lfr = kk + ((lane >> 4) << 3);
#pragma unroll
      for (int i = 0; i < 4; ++i)
        af[i] = *(const hx8*)&sV[(i * 16 + (lane & 15)) * 72 + lfr];
#pragma unroll
      for (int j = 0; j < 4; ++j)
        bf[j] = *(const hx8*)&sK[(w * 64 + j * 16 + (lane & 15)) * 72 + lfr];
#pragma unroll
      for (int i = 0; i < 4; ++i)
#pragma unroll
        for (int j = 0; j < 4; ++j)
          acc[i][j] = __builtin_amdgcn_mfma_f32_16x16x32_f16(af[i], bf[j], acc[i][j], 0, 0, 0);
    }
  }
  float* obase = kvacc + (long)h * (64 * 256);
#pragma unroll
  for (int i = 0; i < 4; ++i)
#pragma unroll
    for (int j = 0; j < 4; ++j) {
      int d0 = i * 16 + ((lane >> 4) << 2);
      int m  = w * 64 + j * 16 + (lane & 15);
#pragma unroll
      for (int r = 0; r < 4; ++r)
        atomicAdd(&obase[(long)(d0 + r) * 256 + m], acc[i][j][r]);
    }
}

// ---------------------------------------------------------------------------
extern "C" void kernel_launch(void* const* d_in, const int* in_sizes, int n_in,
                              void* d_out, int out_size, void* d_ws, size_t ws_size,
                              hipStream_t stream) {
  const float* x     = (const float*)d_in[0];
  const float* pos   = (const float*)d_in[1];
  const float* slp   = (const float*)d_in[2];
  const float* Wv    = (const float*)d_in[3];
  const float* Wo    = (const float*)d_in[4];
  const float* Wpf   = (const float*)d_in[5];
  const float* scale = (const float*)d_in[6];
  const float* offs  = (const float*)d_in[7];
  const float* proj  = (const float*)d_in[8];
  float* out = (float*)d_out;
  char* ws = (char*)d_ws;

  // Workspace arena — total ~184.6 MB (R1's 553 MB core-dumped: ws overflow).
  size_t o = 0;
  auto alloc = [&](size_t bytes) { char* p = ws + o; o += (bytes + 255) & ~(size_t)255; return p; };
  float*    Pb    = (float*)alloc(16777216);       // per-b [4096][1024] f32
  float*    Sb    = (float*)alloc(16777216);
  _Float16* kpr   = (_Float16*)alloc(33554432);    // per-b [H][L][256] f16
  _Float16* qpr   = (_Float16*)alloc(33554432);
  _Float16* Vh    = (_Float16*)alloc(33554432);    // [BL][1024] f16
  _Float16* Zb    = (_Float16*)alloc(33554432);    // [BL][1024] f16
  _Float16* WvT   = (_Float16*)alloc(2097152);
  _Float16* WoT   = (_Float16*)alloc(2097152);
  _Float16* Wpf3T = (_Float16*)alloc(6291456);     // [1024][3072] [hi;hi;lo]
  float*    kvacc = (float*)alloc(4194304);        // [BH][64][256] f32
  _Float16* kvh   = (_Float16*)alloc(2097152);
  (void)ws_size; (void)in_sizes; (void)n_in; (void)out_size;

  // prep
  wt_k<<<dim3(16, 16), 256, 0, stream>>>(Wv, WvT);
  wt_k<<<dim3(16, 16), 256, 0, stream>>>(Wo, WoT);
  wpf3_k<<<dim3(16, 16), 256, 0, stream>>>(Wpf, Wpf3T);
  zero_k<<<256, 256, 0, stream>>>(kvacc, 262144);

  // V = x @ W_v  (A: f32 cast in staging; f16 out), full M=16384
  gemm_bt_k<128, 128, 1, _Float16><<<dim3(8, 128, 1), 256, 0, stream>>>(
      x, WvT, Vh, 1024, 1024, 1024, 1024, 0, 0, 0, 0, 0, 0);

  for (int b = 0; b < B_; ++b) {
    const float* pos_b = pos + (long)b * L_ * 1024;
    const float* slp_b = slp + (long)b * L_ * 1024;
    _Float16* Vh_b  = Vh  + (long)b * L_ * 1024;
    _Float16* Zb_b  = Zb  + (long)b * L_ * 1024;
    float* kvacc_b  = kvacc + (long)b * H_ * 64 * 256;
    _Float16* kvh_b = kvh   + (long)b * H_ * 64 * 256;
    // P,S: split-f16 K=3072 (A mode 2), f32 out
    gemm_bt_k<128, 128, 2, float><<<dim3(8, 32, 1), 256, 0, stream>>>(
        pos_b, Wpf3T, Pb, 3072, 1024, 3072, 1024, 0, 0, 0, 0, 0, 0);
    gemm_bt_k<128, 128, 2, float><<<dim3(8, 32, 1), 256, 0, stream>>>(
        slp_b, Wpf3T, Sb, 3072, 1024, 3072, 1024, 0, 0, 0, 0, 0, 0);
    // fourier features -> qpr, kpr ([H][L][256])
    kf_k<<<32768, 256, 0, stream>>>(Pb, Sb, proj, scale, offs, qpr, kpr);
    // kv (split-K over L with atomics) -> kvacc_b; cast to f16
    kv_k<<<dim3(16, KV_SPLIT), 256, 0, stream>>>(kpr, Vh_b, kvacc_b);
    cast_out_f16_k<<<1024, 256, 0, stream>>>(kvacc_b, kvh_b, 262144);
    // z = q'' @ kvT  (batched over h via blockIdx.z), C -> Zb_b [L][1024]
    gemm_bt_k<128, 64, 0, _Float16><<<dim3(1, 32, 16), 256, 0, stream>>>(
        qpr, kvh_b, Zb_b, 256, 256, 256, 1024,
        0L, (long)L_ * 256, 0L, 16384L, 0L, 64L);
  }
  // out = z @ W_o (f32 out), full M=16384
  gemm_bt_k<128, 128, 0, float><<<dim3(8, 128, 1), 256, 0, stream>>>(
      Zb, WoT, out, 1024, 1024, 1024, 1024, 0, 0, 0, 0, 0, 0);
}

// Round 3
// 1716.427 us; speedup vs baseline: 1.4146x; 1.4146x over previous
//
#include <hip/hip_runtime.h>
#include <hip/hip_bf16.h>
#include <stdint.h>

// ---------------------------------------------------------------------------
// LinearSelfAttention (Performer-style) on gfx950.
//   V     = x @ W_v                     (f16 MFMA, A cast f32->f16 in-staging)
//   P/S   = pos/slopes @ W_pf           (split-f16 virtual K=3072 [hi|lo|hi])
//   prep  : Pb=scale*P, Sb=scale*P+offs*scale*S (in place), norms=||S||/L
//   q',k' = MFMA GEMM vs proj (split-f16 K=192) with sin/cos EPILOGUE fused
//           (R2's kf_k was 40% of runtime at MfmaUtil=0 / VALUBusy=17%)
//   kvT   = sum_l v[l][d] k'[l][m]      (f16 MFMA, LDS transpose, split-K atomics)
//   z     = q'' @ kvT                   (batched f16 MFMA)
//   out   = z @ W_o                     (f16 MFMA, f32 out)
// Workspace ~184.9 MB (R2-proven footprint; R1's 553 MB faulted).
// ---------------------------------------------------------------------------

typedef _Float16 hx8 __attribute__((ext_vector_type(8)));
typedef _Float16 hx4 __attribute__((ext_vector_type(4)));
typedef float    fx4 __attribute__((ext_vector_type(4)));

#define H_   16
#define D_   64
#define L_   4096
#define B_   4
#define BL_  16384
#define KV_SPLIT 8

// ---------------- prep kernels ----------------
// W [1024][1024] f32 -> WT [1024][1024] f16 (WT[n][k] = W[k][n])
__global__ __launch_bounds__(256) void wt_k(const float* __restrict__ W,
                                            _Float16* __restrict__ WT) {
  __shared__ float tile[64][65];
  int t = threadIdx.x; int c = t & 63; int r0 = t >> 6;
  int bx = blockIdx.x * 64, by = blockIdx.y * 64;
  for (int r = r0; r < 64; r += 4) tile[r][c] = W[(long)(by + r) * 1024 + bx + c];
  __syncthreads();
  for (int r = r0; r < 64; r += 4)
    WT[(long)(bx + r) * 1024 + by + c] = (_Float16)tile[c][r];
}

// W_pf -> WT3 [1024][3072] f16 sections: [hi ; hi ; lo] (transposed)
__global__ __launch_bounds__(256) void wpf3_k(const float* __restrict__ W,
                                              _Float16* __restrict__ WT3) {
  __shared__ float tile[64][65];
  int t = threadIdx.x; int c = t & 63; int r0 = t >> 6;
  int bx = blockIdx.x * 64, by = blockIdx.y * 64;
  for (int r = r0; r < 64; r += 4) tile[r][c] = W[(long)(by + r) * 1024 + bx + c];
  __syncthreads();
  for (int r = r0; r < 64; r += 4) {
    float x = tile[c][r];
    _Float16 hi = (_Float16)x;
    _Float16 lo = (_Float16)(x - (float)hi);
    long base = (long)(bx + r) * 3072 + by + c;
    WT3[base] = hi; WT3[base + 1024] = hi; WT3[base + 2048] = lo;
  }
}

// proj [128][64] f32 -> proj3T [128][192] f16 [hi | hi | lo], cnorm folded.
// Section pairing with A=[hi|lo|hi]: hi*hi + lo*hi + hi*lo.
__global__ __launch_bounds__(256) void proj3_k(const float* __restrict__ proj,
                                               _Float16* __restrict__ proj3T) {
  int i = blockIdx.x * 256 + threadIdx.x;
  if (i >= 8192) return;
  int m = i >> 6, d = i & 63;
  float p = 0.35355339059327373f * proj[i];    // 1/64^0.25 folded
  _Float16 hi = (_Float16)p;
  _Float16 lo = (_Float16)(p - (float)hi);
  proj3T[(long)m * 192 + d]       = hi;
  proj3T[(long)m * 192 + 64 + d]  = hi;
  proj3T[(long)m * 192 + 128 + d] = lo;
}

// Per-b: in-place P<-scale*P, S<-scale*P+offs*scale*S; norms[r]=||S_r||/L.
// One wave per (l,h) row of 64 d's.
__global__ __launch_bounds__(256) void prep_qk_k(float* __restrict__ P,
                                                 float* __restrict__ S,
                                                 const float* __restrict__ scale_p,
                                                 const float* __restrict__ offs_p,
                                                 float* __restrict__ norms) {
  int t = threadIdx.x, lane = t & 63, w = t >> 6;
  int row = blockIdx.x * 4 + w;                // row = l*16 + h, 65536 rows
  int h = row & 15;
  long off = (long)row * 64 + lane;
  float p = P[off], s = S[off];
  float sc = scale_p[h], of = offs_p[h];
  P[off] = sc * p;
  S[off] = sc * p + of * sc * s;
  float ss = s * s;
#pragma unroll
  for (int o = 32; o > 0; o >>= 1) ss += __shfl_down(ss, o, 64);
  if (lane == 0) norms[row] = sqrtf(ss) * (1.0f / 4096.0f);
}

__global__ __launch_bounds__(256) void zero_k(float* __restrict__ p, int n4) {
  int i = blockIdx.x * 256 + threadIdx.x;
  int stride = gridDim.x * 256;
  fx4 z = {0.f, 0.f, 0.f, 0.f};
  for (; i < n4; i += stride) ((fx4*)p)[i] = z;
}

__global__ __launch_bounds__(256) void cast_out_f16_k(const float* __restrict__ in,
                                                      _Float16* __restrict__ out, int n) {
  int i = blockIdx.x * 256 + threadIdx.x;
  int stride = gridDim.x * 256;
  for (; i < n; i += stride) out[i] = (_Float16)in[i];
}

// ---------------- generic f16 MFMA GEMM:  C[M][N] = A[M][K] @ BT[N][K]^T ----
// BK=64, 256 threads, 4 waves 2x2; XOR-swizzled LDS (conflict-free b128).
// AMODE: 0 = A f16; 1 = A f32 (cast in staging); 2 = A f32, virtual-K split
//        [hi|lo|hi] in sections of (1<<SECSH) (SECSH=10: K=3072; 6: K=192).
// EPI:   0 = plain store; 1 = fourier: angle->sin/cos, write [H][L][256] f16
//        (rn = ratio*norms[row] if norms else ratio).
template<int BM, int BN, int AMODE, int SECSH, int EPI, typename OUT_T>
__global__ __launch_bounds__(256) void gemm_bt_k(
    const void* __restrict__ Av, const _Float16* __restrict__ BT,
    OUT_T* __restrict__ C, int K, int lda, int ldb, int ldc,
    long sAb, long sAh, long sBb, long sBh, long sCb, long sCh,
    const float* __restrict__ norms)
{
  __shared__ __align__(16) _Float16 sA[BM * 64];
  __shared__ __align__(16) _Float16 sB[BN * 64];
  const int t = threadIdx.x;
  const int lane = t & 63;
  const int w = t >> 6;
  const int wm = w >> 1, wn = w & 1;
  const int bx = blockIdx.x, by = blockIdx.y, bz = blockIdx.z;
  long aoff = (long)(bz >> 4) * sAb + (long)(bz & 15) * sAh;
  BT += (long)(bz >> 4) * sBb + (long)(bz & 15) * sBh;
  C  += (long)(bz >> 4) * sCb + (long)(bz & 15) * sCh;
  const _Float16* A16 = (const _Float16*)Av + aoff;
  const float*    A32 = (const float*)Av + aoff;
  constexpr int WTM = BM / 32, WTN = BN / 32;
  fx4 acc[WTM][WTN];
#pragma unroll
  for (int i = 0; i < WTM; ++i)
#pragma unroll
    for (int j = 0; j < WTN; ++j) acc[i][j] = (fx4){0.f, 0.f, 0.f, 0.f};

  for (int k0 = 0; k0 < K; k0 += 64) {
    __syncthreads();
    // ---- stage A tile [BM x 64] ----
    if constexpr (AMODE == 0) {
#pragma unroll
      for (int i = 0; i < BM / 32; ++i) {
        int s = i * 256 + t; int row = s >> 3; int kc = (s & 7) ^ (row & 7);
        *(uint4*)&sA[s * 8] =
            *(const uint4*)&A16[(long)(by * BM + row) * lda + k0 + kc * 8];
      }
    } else {
      int mode, cs;
      if constexpr (AMODE == 2) { mode = k0 >> SECSH; cs = k0 & ((1 << SECSH) - 1); }
      else                      { mode = 0;           cs = k0;                      }
#pragma unroll
      for (int i = 0; i < BM / 32; ++i) {
        int s = i * 256 + t; int row = s >> 3; int kc = (s & 7) ^ (row & 7);
        const float* src = A32 + (long)(by * BM + row) * lda + cs + kc * 8;
        fx4 v0 = *(const fx4*)src;
        fx4 v1 = *(const fx4*)(src + 4);
        hx8 hv;
        if (mode != 1) {
#pragma unroll
          for (int e = 0; e < 4; ++e) { hv[e] = (_Float16)v0[e]; hv[4 + e] = (_Float16)v1[e]; }
        } else {
#pragma unroll
          for (int e = 0; e < 4; ++e) {
            _Float16 h0 = (_Float16)v0[e]; hv[e]     = (_Float16)(v0[e] - (float)h0);
            _Float16 h1 = (_Float16)v1[e]; hv[4 + e] = (_Float16)(v1[e] - (float)h1);
          }
        }
        *(hx8*)&sA[s * 8] = hv;
      }
    }
    // ---- stage B tile [BN x 64] ----
#pragma unroll
    for (int i = 0; i < BN / 32; ++i) {
      int s = i * 256 + t; int row = s >> 3; int kc = (s & 7) ^ (row & 7);
      *(uint4*)&sB[s * 8] =
          *(const uint4*)&BT[(long)(bx * BN + row) * ldb + k0 + kc * 8];
    }
    __syncthreads();
#pragma unroll
    for (int kk = 0; kk < 64; kk += 32) {
      hx8 af[WTM], bf[WTN];
      int kcb = (kk >> 3) + (lane >> 4);
#pragma unroll
      for (int i = 0; i < WTM; ++i) {
        int r = wm * (BM / 2) + i * 16 + (lane & 15);
        af[i] = *(const hx8*)&sA[(r * 8 + (kcb ^ (r & 7))) * 8];
      }
#pragma unroll
      for (int j = 0; j < WTN; ++j) {
        int r = wn * (BN / 2) + j * 16 + (lane & 15);
        bf[j] = *(const hx8*)&sB[(r * 8 + (kcb ^ (r & 7))) * 8];
      }
#pragma unroll
      for (int i = 0; i < WTM; ++i)
#pragma unroll
        for (int j = 0; j < WTN; ++j)
          acc[i][j] = __builtin_amdgcn_mfma_f32_16x16x32_f16(af[i], bf[j], acc[i][j], 0, 0, 0);
    }
  }
  if constexpr (EPI == 0) {
#pragma unroll
    for (int i = 0; i < WTM; ++i) {
#pragma unroll
      for (int j = 0; j < WTN; ++j) {
        int rowb = by * BM + wm * (BM / 2) + i * 16 + ((lane >> 4) << 2);
        int col  = bx * BN + wn * (BN / 2) + j * 16 + (lane & 15);
#pragma unroll
        for (int r = 0; r < 4; ++r)
          C[(long)(rowb + r) * ldc + col] = (OUT_T)acc[i][j][r];
      }
    }
  } else {
    const float inv2pi = 0.15915494309189535f;
    const float ratio  = 0.08838834764831845f;   // 1/sqrt(128)
    const bool useN = (norms != nullptr);
#pragma unroll
    for (int i = 0; i < WTM; ++i) {
#pragma unroll
      for (int j = 0; j < WTN; ++j) {
        int rowb = by * BM + wm * (BM / 2) + i * 16 + ((lane >> 4) << 2);
        int col  = bx * BN + wn * (BN / 2) + j * 16 + (lane & 15);
#pragma unroll
        for (int r = 0; r < 4; ++r) {
          int row = rowb + r;                     // row = l*16 + h
          float rn = useN ? ratio * norms[row] : ratio;
          long ob = ((long)(row & 15) * 4096 + (row >> 4)) * 256;
          float v = acc[i][j][r] * inv2pi;
          v -= floorf(v);                         // revolutions in [0,1)
          C[ob + col]       = (OUT_T)(rn * __builtin_amdgcn_sinf(v));
          C[ob + 128 + col] = (OUT_T)(rn * __builtin_amdgcn_cosf(v));
        }
      }
    }
  }
}

// ---------------- kv kernel (per-b): kvT[d][m] = sum_l v[l][d] * k'[l][m] ---
__global__ __launch_bounds__(256) void kv_k(const _Float16* __restrict__ Kp,
                                            const _Float16* __restrict__ Vhb,
                                            float* __restrict__ kvacc)
{
  __shared__ __align__(16) _Float16 sK[256 * 72];   // [m][l] stride 72
  __shared__ __align__(16) _Float16 sV[64 * 72];    // [d][l]
  const int t = threadIdx.x, lane = t & 63, w = t >> 6;
  const int h = blockIdx.x;
  const int l0 = blockIdx.y * (L_ / KV_SPLIT);
  fx4 acc[4][4];
#pragma unroll
  for (int i = 0; i < 4; ++i)
#pragma unroll
    for (int j = 0; j < 4; ++j) acc[i][j] = (fx4){0.f, 0.f, 0.f, 0.f};
  const _Float16* Kbase = Kp + (long)h * L_ * 256;
  for (int kt = 0; kt < L_ / KV_SPLIT; kt += 64) {
    __syncthreads();
#pragma unroll
    for (int i = 0; i < 8; ++i) {               // k' tile: 64 l x 256 m, transpose
      int mc = w + 4 * i;                       // 0..31 (wave-uniform)
      hx8 vv = *(const hx8*)&Kbase[(long)(l0 + kt + lane) * 256 + mc * 8];
#pragma unroll
      for (int e = 0; e < 8; ++e) sK[(mc * 8 + e) * 72 + lane] = vv[e];
    }
#pragma unroll
    for (int i = 0; i < 2; ++i) {               // v tile: 64 l x 64 d, transpose
      int dc = w + 4 * i;                       // 0..7
      hx8 vv = *(const hx8*)&Vhb[(long)(l0 + kt + lane) * 1024 + h * 64 + dc * 8];
#pragma unroll
      for (int e = 0; e < 8; ++e) sV[(dc * 8 + e) * 72 + lane] = vv[e];
    }
    __syncthreads();
#pragma unroll
    for (int kk = 0; kk < 64; kk += 32) {
      hx8 af[4], bf[4];
      int lfr = kk + ((lane >> 4) << 3);
#pragma unroll
      for (int i = 0; i < 4; ++i)
        af[i] = *(const hx8*)&sV[(i * 16 + (lane & 15)) * 72 + lfr];
#pragma unroll
      for (int j = 0; j < 4; ++j)
        bf[j] = *(const hx8*)&sK[(w * 64 + j * 16 + (lane & 15)) * 72 + lfr];
#pragma unroll
      for (int i = 0; i < 4; ++i)
#pragma unroll
        for (int j = 0; j < 4; ++j)
          acc[i][j] = __builtin_amdgcn_mfma_f32_16x16x32_f16(af[i], bf[j], acc[i][j], 0, 0, 0);
    }
  }
  float* obase = kvacc + (long)h * (64 * 256);
#pragma unroll
  for (int i = 0; i < 4; ++i)
#pragma unroll
    for (int j = 0; j < 4; ++j) {
      int d0 = i * 16 + ((lane >> 4) << 2);
      int m  = w * 64 + j * 16 + (lane & 15);
#pragma unroll
      for (int r = 0; r < 4; ++r)
        atomicAdd(&obase[(long)(d0 + r) * 256 + m], acc[i][j][r]);
    }
}

// ---------------------------------------------------------------------------
extern "C" void kernel_launch(void* const* d_in, const int* in_sizes, int n_in,
                              void* d_out, int out_size, void* d_ws, size_t ws_size,
                              hipStream_t stream) {
  const float* x     = (const float*)d_in[0];
  const float* pos   = (const float*)d_in[1];
  const float* slp   = (const float*)d_in[2];
  const float* Wv    = (const float*)d_in[3];
  const float* Wo    = (const float*)d_in[4];
  const float* Wpf   = (const float*)d_in[5];
  const float* scale = (const float*)d_in[6];
  const float* offs  = (const float*)d_in[7];
  const float* proj  = (const float*)d_in[8];
  float* out = (float*)d_out;
  char* ws = (char*)d_ws;

  size_t o = 0;
  auto alloc = [&](size_t bytes) { char* p = ws + o; o += (bytes + 255) & ~(size_t)255; return p; };
  float*    Pb     = (float*)alloc(16777216);      // per-b [L][1024] f32 (in-place qp)
  float*    Sb     = (float*)alloc(16777216);      // per-b (in-place kp)
  _Float16* kpr    = (_Float16*)alloc(33554432);   // per-b [H][L][256] f16
  _Float16* qpr    = (_Float16*)alloc(33554432);
  _Float16* Vh     = (_Float16*)alloc(33554432);   // [BL][1024] f16
  _Float16* Zb     = (_Float16*)alloc(33554432);   // [BL][1024] f16
  _Float16* WvT    = (_Float16*)alloc(2097152);
  _Float16* WoT    = (_Float16*)alloc(2097152);
  _Float16* Wpf3T  = (_Float16*)alloc(6291456);    // [1024][3072] [hi;hi;lo]
  _Float16* proj3T = (_Float16*)alloc(49152);      // [128][192] [hi|hi|lo]
  float*    norms  = (float*)alloc(262144);        // per-b [L*H] f32
  float*    kvacc  = (float*)alloc(4194304);       // [BH][64][256] f32
  _Float16* kvh    = (_Float16*)alloc(2097152);
  (void)ws_size; (void)in_sizes; (void)n_in; (void)out_size;

  // prep
  wt_k<<<dim3(16, 16), 256, 0, stream>>>(Wv, WvT);
  wt_k<<<dim3(16, 16), 256, 0, stream>>>(Wo, WoT);
  wpf3_k<<<dim3(16, 16), 256, 0, stream>>>(Wpf, Wpf3T);
  proj3_k<<<32, 256, 0, stream>>>(proj, proj3T);
  zero_k<<<256, 256, 0, stream>>>(kvacc, 262144);

  // V = x @ W_v  (A: f32 cast in staging; f16 out), full M=16384
  gemm_bt_k<128, 128, 1, 0, 0, _Float16><<<dim3(8, 128, 1), 256, 0, stream>>>(
      x, WvT, Vh, 1024, 1024, 1024, 1024, 0, 0, 0, 0, 0, 0, nullptr);

  for (int b = 0; b < B_; ++b) {
    const float* pos_b = pos + (long)b * L_ * 1024;
    const float* slp_b = slp + (long)b * L_ * 1024;
    _Float16* Vh_b  = Vh  + (long)b * L_ * 1024;
    _Float16* Zb_b  = Zb  + (long)b * L_ * 1024;
    float* kvacc_b  = kvacc + (long)b * H_ * 64 * 256;
    _Float16* kvh_b = kvh   + (long)b * H_ * 64 * 256;
    // P,S: split-f16 K=3072, f32 out
    gemm_bt_k<128, 128, 2, 10, 0, float><<<dim3(8, 32, 1), 256, 0, stream>>>(
        pos_b, Wpf3T, Pb, 3072, 1024, 3072, 1024, 0, 0, 0, 0, 0, 0, nullptr);
    gemm_bt_k<128, 128, 2, 10, 0, float><<<dim3(8, 32, 1), 256, 0, stream>>>(
        slp_b, Wpf3T, Sb, 3072, 1024, 3072, 1024, 0, 0, 0, 0, 0, 0, nullptr);
    // fold scale/offs in place + slope norms
    prep_qk_k<<<16384, 256, 0, stream>>>(Pb, Sb, scale, offs, norms);
    // q',k' via MFMA GEMM vs proj3T (K=192 split-f16), sin/cos epilogue
    gemm_bt_k<128, 128, 2, 6, 1, _Float16><<<dim3(1, 512, 1), 256, 0, stream>>>(
        Pb, proj3T, qpr, 192, 64, 192, 0, 0, 0, 0, 0, 0, 0, norms);
    gemm_bt_k<128, 128, 2, 6, 1, _Float16><<<dim3(1, 512, 1), 256, 0, stream>>>(
        Sb, proj3T, kpr, 192, 64, 192, 0, 0, 0, 0, 0, 0, 0, nullptr);
    // kv (split-K over L with atomics) -> kvacc_b; cast to f16
    kv_k<<<dim3(16, KV_SPLIT), 256, 0, stream>>>(kpr, Vh_b, kvacc_b);
    cast_out_f16_k<<<1024, 256, 0, stream>>>(kvacc_b, kvh_b, 262144);
    // z = q'' @ kvT  (batched over h via blockIdx.z), C -> Zb_b [L][1024]
    gemm_bt_k<128, 64, 0, 0, 0, _Float16><<<dim3(1, 32, 16), 256, 0, stream>>>(
        qpr, kvh_b, Zb_b, 256, 256, 256, 1024,
        0L, (long)L_ * 256, 0L, 16384L, 0L, 64L, nullptr);
  }
  // out = z @ W_o (f32 out), full M=16384
  gemm_bt_k<128, 128, 0, 0, 0, float><<<dim3(8, 128, 1), 256, 0, stream>>>(
      Zb, WoT, out, 1024, 1024, 1024, 1024, 0, 0, 0, 0, 0, 0, nullptr);
}

// Round 4
// 1098.248 us; speedup vs baseline: 2.2109x; 1.5629x over previous
//
#include <hip/hip_runtime.h>
#include <hip/hip_bf16.h>
#include <stdint.h>

// ---------------------------------------------------------------------------
// LinearSelfAttention (Performer-style) on gfx950.
//   V     = x @ W_v                     (f16 MFMA, A cast f32->f16 in-staging)
//   P/S   = pos/slopes @ W_pf           (split-f16 virtual K=3072 [hi|lo|hi])
//           P-epilogue folds scale; S-epilogue folds kp-combine + slope norms
//   q',k' = MFMA GEMM vs proj (split-f16 K=192), sin/cos epilogue, q+k merged
//   kvT   = sum_l v[l][d] k'[l][m]      (f16 MFMA, LDS transpose, split-K=16)
//   z     = q'' @ kvT                   (batched f16 MFMA)
//   out   = z @ W_o                     (f16 MFMA, f32 out)
// R3 post-mortem: P/S GEMMs were 65% of runtime at Occupancy 10.7% (256-block
// grids = 1 block/CU). This round: 2-b super-batches (512 blocks), XCD-aware
// grid transpose (M-dim = blockIdx.x so A-row sharers hit the same XCD L2),
// prep fused into epilogues. Workspace 218.6 MB.
// ---------------------------------------------------------------------------

typedef _Float16 hx8 __attribute__((ext_vector_type(8)));
typedef _Float16 hx4 __attribute__((ext_vector_type(4)));
typedef float    fx4 __attribute__((ext_vector_type(4)));

#define H_   16
#define D_   64
#define L_   4096
#define B_   4
#define BL_  16384
#define KV_SPLIT 16

// ---------------- prep kernels ----------------
// W [1024][1024] f32 -> WT [1024][1024] f16 (WT[n][k] = W[k][n])
__global__ __launch_bounds__(256) void wt_k(const float* __restrict__ W,
                                            _Float16* __restrict__ WT) {
  __shared__ float tile[64][65];
  int t = threadIdx.x; int c = t & 63; int r0 = t >> 6;
  int bx = blockIdx.x * 64, by = blockIdx.y * 64;
  for (int r = r0; r < 64; r += 4) tile[r][c] = W[(long)(by + r) * 1024 + bx + c];
  __syncthreads();
  for (int r = r0; r < 64; r += 4)
    WT[(long)(bx + r) * 1024 + by + c] = (_Float16)tile[c][r];
}

// W_pf -> WT3 [1024][3072] f16 sections: [hi ; hi ; lo] (transposed)
__global__ __launch_bounds__(256) void wpf3_k(const float* __restrict__ W,
                                              _Float16* __restrict__ WT3) {
  __shared__ float tile[64][65];
  int t = threadIdx.x; int c = t & 63; int r0 = t >> 6;
  int bx = blockIdx.x * 64, by = blockIdx.y * 64;
  for (int r = r0; r < 64; r += 4) tile[r][c] = W[(long)(by + r) * 1024 + bx + c];
  __syncthreads();
  for (int r = r0; r < 64; r += 4) {
    float x = tile[c][r];
    _Float16 hi = (_Float16)x;
    _Float16 lo = (_Float16)(x - (float)hi);
    long base = (long)(bx + r) * 3072 + by + c;
    WT3[base] = hi; WT3[base + 1024] = hi; WT3[base + 2048] = lo;
  }
}

// proj [128][64] f32 -> proj3T [128][192] f16 [hi | hi | lo], cnorm folded.
__global__ __launch_bounds__(256) void proj3_k(const float* __restrict__ proj,
                                               _Float16* __restrict__ proj3T) {
  int i = blockIdx.x * 256 + threadIdx.x;
  if (i >= 8192) return;
  int m = i >> 6, d = i & 63;
  float p = 0.35355339059327373f * proj[i];    // 1/64^0.25 folded
  _Float16 hi = (_Float16)p;
  _Float16 lo = (_Float16)(p - (float)hi);
  proj3T[(long)m * 192 + d]       = hi;
  proj3T[(long)m * 192 + 64 + d]  = hi;
  proj3T[(long)m * 192 + 128 + d] = lo;
}

__global__ __launch_bounds__(256) void zero_k(float* __restrict__ p, int n4) {
  int i = blockIdx.x * 256 + threadIdx.x;
  int stride = gridDim.x * 256;
  fx4 z = {0.f, 0.f, 0.f, 0.f};
  for (; i < n4; i += stride) ((fx4*)p)[i] = z;
}

__global__ __launch_bounds__(256) void cast_out_f16_k(const float* __restrict__ in,
                                                      _Float16* __restrict__ out, int n) {
  int i = blockIdx.x * 256 + threadIdx.x;
  int stride = gridDim.x * 256;
  for (; i < n; i += stride) out[i] = (_Float16)in[i];
}

// ---------------- generic f16 MFMA GEMM:  C[M][N] = A[M][K] @ BT[N][K]^T ----
// BK=64, 256 threads, 4 waves 2x2; XOR-swizzled LDS (conflict-free b128).
// GRID: blockIdx.x = M-tile (by), blockIdx.y = N-tile (bx) — XCD-aware: blocks
// sharing A rows differ by gridDim.x in linear id => same id%8 => same XCD L2.
// AMODE: 0 = A f16; 1 = A f32 (cast in staging); 2 = A f32, virtual-K split
//        [hi|lo|hi] in sections of (1<<SECSH) (SECSH=10: K=3072; 6: K=192).
// EPI: 0 plain store | 1 fourier sin/cos (norms if (bz&15)==0) |
//      2 C = scp[h]*acc | 3 C = Pprev + ofp[h]*scp[h]*acc, nout=||acc_row||/L.
template<int BM, int BN, int AMODE, int SECSH, int EPI, typename OUT_T>
__global__ __launch_bounds__(256) void gemm_bt_k(
    const void* __restrict__ Av, const _Float16* __restrict__ BT,
    OUT_T* __restrict__ C, int K, int lda, int ldb, int ldc,
    long sAb, long sAh, long sBb, long sBh, long sCb, long sCh,
    const float* __restrict__ norms, const float* __restrict__ scp,
    const float* __restrict__ ofp, const float* __restrict__ Pprev,
    float* __restrict__ nout)
{
  __shared__ __align__(16) _Float16 sA[BM * 64];
  __shared__ __align__(16) _Float16 sB[BN * 64];
  const int t = threadIdx.x;
  const int lane = t & 63;
  const int w = t >> 6;
  const int wm = w >> 1, wn = w & 1;
  const int by = blockIdx.x, bx = blockIdx.y, bz = blockIdx.z;
  long aoff = (long)(bz >> 4) * sAb + (long)(bz & 15) * sAh;
  BT += (long)(bz >> 4) * sBb + (long)(bz & 15) * sBh;
  C  += (long)(bz >> 4) * sCb + (long)(bz & 15) * sCh;
  const _Float16* A16 = (const _Float16*)Av + aoff;
  const float*    A32 = (const float*)Av + aoff;
  constexpr int WTM = BM / 32, WTN = BN / 32;
  fx4 acc[WTM][WTN];
#pragma unroll
  for (int i = 0; i < WTM; ++i)
#pragma unroll
    for (int j = 0; j < WTN; ++j) acc[i][j] = (fx4){0.f, 0.f, 0.f, 0.f};

  for (int k0 = 0; k0 < K; k0 += 64) {
    __syncthreads();
    // ---- stage A tile [BM x 64] ----
    if constexpr (AMODE == 0) {
#pragma unroll
      for (int i = 0; i < BM / 32; ++i) {
        int s = i * 256 + t; int row = s >> 3; int kc = (s & 7) ^ (row & 7);
        *(uint4*)&sA[s * 8] =
            *(const uint4*)&A16[(long)(by * BM + row) * lda + k0 + kc * 8];
      }
    } else {
      int mode, cs;
      if constexpr (AMODE == 2) { mode = k0 >> SECSH; cs = k0 & ((1 << SECSH) - 1); }
      else                      { mode = 0;           cs = k0;                      }
#pragma unroll
      for (int i = 0; i < BM / 32; ++i) {
        int s = i * 256 + t; int row = s >> 3; int kc = (s & 7) ^ (row & 7);
        const float* src = A32 + (long)(by * BM + row) * lda + cs + kc * 8;
        fx4 v0 = *(const fx4*)src;
        fx4 v1 = *(const fx4*)(src + 4);
        hx8 hv;
        if (mode != 1) {
#pragma unroll
          for (int e = 0; e < 4; ++e) { hv[e] = (_Float16)v0[e]; hv[4 + e] = (_Float16)v1[e]; }
        } else {
#pragma unroll
          for (int e = 0; e < 4; ++e) {
            _Float16 h0 = (_Float16)v0[e]; hv[e]     = (_Float16)(v0[e] - (float)h0);
            _Float16 h1 = (_Float16)v1[e]; hv[4 + e] = (_Float16)(v1[e] - (float)h1);
          }
        }
        *(hx8*)&sA[s * 8] = hv;
      }
    }
    // ---- stage B tile [BN x 64] ----
#pragma unroll
    for (int i = 0; i < BN / 32; ++i) {
      int s = i * 256 + t; int row = s >> 3; int kc = (s & 7) ^ (row & 7);
      *(uint4*)&sB[s * 8] =
          *(const uint4*)&BT[(long)(bx * BN + row) * ldb + k0 + kc * 8];
    }
    __syncthreads();
#pragma unroll
    for (int kk = 0; kk < 64; kk += 32) {
      hx8 af[WTM], bf[WTN];
      int kcb = (kk >> 3) + (lane >> 4);
#pragma unroll
      for (int i = 0; i < WTM; ++i) {
        int r = wm * (BM / 2) + i * 16 + (lane & 15);
        af[i] = *(const hx8*)&sA[(r * 8 + (kcb ^ (r & 7))) * 8];
      }
#pragma unroll
      for (int j = 0; j < WTN; ++j) {
        int r = wn * (BN / 2) + j * 16 + (lane & 15);
        bf[j] = *(const hx8*)&sB[(r * 8 + (kcb ^ (r & 7))) * 8];
      }
#pragma unroll
      for (int i = 0; i < WTM; ++i)
#pragma unroll
        for (int j = 0; j < WTN; ++j)
          acc[i][j] = __builtin_amdgcn_mfma_f32_16x16x32_f16(af[i], bf[j], acc[i][j], 0, 0, 0);
    }
  }
  if constexpr (EPI == 0) {
#pragma unroll
    for (int i = 0; i < WTM; ++i) {
#pragma unroll
      for (int j = 0; j < WTN; ++j) {
        int rowb = by * BM + wm * (BM / 2) + i * 16 + ((lane >> 4) << 2);
        int col  = bx * BN + wn * (BN / 2) + j * 16 + (lane & 15);
#pragma unroll
        for (int r = 0; r < 4; ++r)
          C[(long)(rowb + r) * ldc + col] = (OUT_T)acc[i][j][r];
      }
    }
  } else if constexpr (EPI == 1) {
    const float inv2pi = 0.15915494309189535f;
    const float ratio  = 0.08838834764831845f;   // 1/sqrt(128)
    const bool useN = ((bz & 15) == 0);
#pragma unroll
    for (int i = 0; i < WTM; ++i) {
#pragma unroll
      for (int j = 0; j < WTN; ++j) {
        int rowb = by * BM + wm * (BM / 2) + i * 16 + ((lane >> 4) << 2);
        int col  = bx * BN + wn * (BN / 2) + j * 16 + (lane & 15);
#pragma unroll
        for (int r = 0; r < 4; ++r) {
          int row = rowb + r;                     // row = l*16 + h
          float rn = ratio * (useN ? norms[row] : 1.0f);
          long ob = ((long)(row & 15) * 4096 + (row >> 4)) * 256;
          float v = acc[i][j][r] * inv2pi;
          v -= floorf(v);                         // revolutions in [0,1)
          C[ob + col]       = (OUT_T)(rn * __builtin_amdgcn_sinf(v));
          C[ob + 128 + col] = (OUT_T)(rn * __builtin_amdgcn_cosf(v));
        }
      }
    }
  } else if constexpr (EPI == 2) {
    const int h = ((bx * BN) >> 6) + wn;          // BN=128: 2 heads/block
    const float sc = scp[h];
#pragma unroll
    for (int i = 0; i < WTM; ++i) {
#pragma unroll
      for (int j = 0; j < WTN; ++j) {
        int rowb = by * BM + wm * (BM / 2) + i * 16 + ((lane >> 4) << 2);
        int col  = bx * BN + wn * (BN / 2) + j * 16 + (lane & 15);
#pragma unroll
        for (int r = 0; r < 4; ++r)
          C[(long)(rowb + r) * ldc + col] = (OUT_T)(sc * acc[i][j][r]);
      }
    }
  } else {                                        // EPI == 3
    const int h = ((bx * BN) >> 6) + wn;
    const float sc = scp[h], of = ofp[h];
#pragma unroll
    for (int i = 0; i < WTM; ++i) {
      float sq[4] = {0.f, 0.f, 0.f, 0.f};
      int rowb = by * BM + wm * (BM / 2) + i * 16 + ((lane >> 4) << 2);
#pragma unroll
      for (int j = 0; j < WTN; ++j) {
        int col = bx * BN + wn * (BN / 2) + j * 16 + (lane & 15);
#pragma unroll
        for (int r = 0; r < 4; ++r) {
          float a = acc[i][j][r];
          sq[r] += a * a;
          C[(long)(rowb + r) * ldc + col] =
              (OUT_T)(Pprev[(long)(rowb + r) * ldc + col] + of * sc * a);
        }
      }
#pragma unroll
      for (int r = 0; r < 4; ++r) {               // 64-col norm: 4 j's x 16 lanes
        float s = sq[r];
        s += __shfl_xor(s, 1); s += __shfl_xor(s, 2);
        s += __shfl_xor(s, 4); s += __shfl_xor(s, 8);
        if ((lane & 15) == 0)
          nout[(long)(rowb + r) * 16 + h] = sqrtf(s) * (1.0f / 4096.0f);
      }
    }
  }
}

// ---------------- kv kernel (per-b): kvT[d][m] = sum_l v[l][d] * k'[l][m] ---
__global__ __launch_bounds__(256) void kv_k(const _Float16* __restrict__ Kp,
                                            const _Float16* __restrict__ Vhb,
                                            float* __restrict__ kvacc)
{
  __shared__ __align__(16) _Float16 sK[256 * 72];   // [m][l] stride 72
  __shared__ __align__(16) _Float16 sV[64 * 72];    // [d][l]
  const int t = threadIdx.x, lane = t & 63, w = t >> 6;
  const int h = blockIdx.x;
  const int l0 = blockIdx.y * (L_ / KV_SPLIT);
  fx4 acc[4][4];
#pragma unroll
  for (int i = 0; i < 4; ++i)
#pragma unroll
    for (int j = 0; j < 4; ++j) acc[i][j] = (fx4){0.f, 0.f, 0.f, 0.f};
  const _Float16* Kbase = Kp + (long)h * L_ * 256;
  for (int kt = 0; kt < L_ / KV_SPLIT; kt += 64) {
    __syncthreads();
#pragma unroll
    for (int i = 0; i < 8; ++i) {               // k' tile: 64 l x 256 m, transpose
      int mc = w + 4 * i;                       // 0..31 (wave-uniform)
      hx8 vv = *(const hx8*)&Kbase[(long)(l0 + kt + lane) * 256 + mc * 8];
#pragma unroll
      for (int e = 0; e < 8; ++e) sK[(mc * 8 + e) * 72 + lane] = vv[e];
    }
#pragma unroll
    for (int i = 0; i < 2; ++i) {               // v tile: 64 l x 64 d, transpose
      int dc = w + 4 * i;                       // 0..7
      hx8 vv = *(const hx8*)&Vhb[(long)(l0 + kt + lane) * 1024 + h * 64 + dc * 8];
#pragma unroll
      for (int e = 0; e < 8; ++e) sV[(dc * 8 + e) * 72 + lane] = vv[e];
    }
    __syncthreads();
#pragma unroll
    for (int kk = 0; kk < 64; kk += 32) {
      hx8 af[4], bf[4];
      int lfr = kk + ((lane >> 4) << 3);
#pragma unroll
      for (int i = 0; i < 4; ++i)
        af[i] = *(const hx8*)&sV[(i * 16 + (lane & 15)) * 72 + lfr];
#pragma unroll
      for (int j = 0; j < 4; ++j)
        bf[j] = *(const hx8*)&sK[(w * 64 + j * 16 + (lane & 15)) * 72 + lfr];
#pragma unroll
      for (int i = 0; i < 4; ++i)
#pragma unroll
        for (int j = 0; j < 4; ++j)
          acc[i][j] = __builtin_amdgcn_mfma_f32_16x16x32_f16(af[i], bf[j], acc[i][j], 0, 0, 0);
    }
  }
  float* obase = kvacc + (long)h * (64 * 256);
#pragma unroll
  for (int i = 0; i < 4; ++i)
#pragma unroll
    for (int j = 0; j < 4; ++j) {
      int d0 = i * 16 + ((lane >> 4) << 2);
      int m  = w * 64 + j * 16 + (lane & 15);
#pragma unroll
      for (int r = 0; r < 4; ++r)
        atomicAdd(&obase[(long)(d0 + r) * 256 + m], acc[i][j][r]);
    }
}

// ---------------------------------------------------------------------------
extern "C" void kernel_launch(void* const* d_in, const int* in_sizes, int n_in,
                              void* d_out, int out_size, void* d_ws, size_t ws_size,
                              hipStream_t stream) {
  const float* x     = (const float*)d_in[0];
  const float* pos   = (const float*)d_in[1];
  const float* slp   = (const float*)d_in[2];
  const float* Wv    = (const float*)d_in[3];
  const float* Wo    = (const float*)d_in[4];
  const float* Wpf   = (const float*)d_in[5];
  const float* scale = (const float*)d_in[6];
  const float* offs  = (const float*)d_in[7];
  const float* proj  = (const float*)d_in[8];
  float* out = (float*)d_out;
  char* ws = (char*)d_ws;

  // Arena ~218.6 MB. NOTE: Sb must follow Pb contiguously (fourier sAh stride),
  // kpr must follow qpr contiguously (fourier sCh stride).
  size_t o = 0;
  auto alloc = [&](size_t bytes) { char* p = ws + o; o += (bytes + 255) & ~(size_t)255; return p; };
  float*    Pb     = (float*)alloc(33554432);      // [2][4096][1024] f32 (= qp, scaled)
  float*    Sb     = (float*)alloc(33554432);      // (= kp)          == Pb + 8388608
  _Float16* qpr    = (_Float16*)alloc(33554432);   // per-b [H][L][256] f16
  _Float16* kpr    = (_Float16*)alloc(33554432);   //                 == qpr + 16777216
  _Float16* Vh     = (_Float16*)alloc(33554432);   // [BL][1024] f16
  _Float16* Zb     = (_Float16*)alloc(33554432);   // [BL][1024] f16
  _Float16* WvT    = (_Float16*)alloc(2097152);
  _Float16* WoT    = (_Float16*)alloc(2097152);
  _Float16* Wpf3T  = (_Float16*)alloc(6291456);    // [1024][3072] [hi;hi;lo]
  _Float16* proj3T = (_Float16*)alloc(49152);      // [128][192] [hi|hi|lo]
  float*    normsB = (float*)alloc(524288);        // [8192][16] f32 per super-batch
  float*    kvacc  = (float*)alloc(4194304);       // [BH][64][256] f32
  _Float16* kvh    = (_Float16*)alloc(2097152);
  (void)ws_size; (void)in_sizes; (void)n_in; (void)out_size;

  // prep
  wt_k<<<dim3(16, 16), 256, 0, stream>>>(Wv, WvT);
  wt_k<<<dim3(16, 16), 256, 0, stream>>>(Wo, WoT);
  wpf3_k<<<dim3(16, 16), 256, 0, stream>>>(Wpf, Wpf3T);
  proj3_k<<<32, 256, 0, stream>>>(proj, proj3T);
  zero_k<<<256, 256, 0, stream>>>(kvacc, 262144);

  // V = x @ W_v (A: f32 cast in staging; f16 out), M=16384, grid (M,N)-swapped
  gemm_bt_k<128, 128, 1, 0, 0, _Float16><<<dim3(128, 8, 1), 256, 0, stream>>>(
      x, WvT, Vh, 1024, 1024, 1024, 1024, 0, 0, 0, 0, 0, 0,
      nullptr, nullptr, nullptr, nullptr, nullptr);

  for (int sb = 0; sb < 2; ++sb) {
    const float* pos_sb = pos + (long)sb * 8192 * 1024;
    const float* slp_sb = slp + (long)sb * 8192 * 1024;
    // P = scale * (pos @ W_pf): split-f16 K=3072, EPI=2, M=8192 (2 b's)
    gemm_bt_k<128, 128, 2, 10, 2, float><<<dim3(64, 8, 1), 256, 0, stream>>>(
        pos_sb, Wpf3T, Pb, 3072, 1024, 3072, 1024, 0, 0, 0, 0, 0, 0,
        nullptr, scale, nullptr, nullptr, nullptr);
    // S: kp = P + offs*scale*acc, + slope norms (EPI=3)
    gemm_bt_k<128, 128, 2, 10, 3, float><<<dim3(64, 8, 1), 256, 0, stream>>>(
        slp_sb, Wpf3T, Sb, 3072, 1024, 3072, 1024, 0, 0, 0, 0, 0, 0,
        nullptr, scale, offs, Pb, normsB);

    for (int bb = 0; bb < 2; ++bb) {
      int b = sb * 2 + bb;
      _Float16* Vh_b  = Vh + (long)b * L_ * 1024;
      _Float16* Zb_b  = Zb + (long)b * L_ * 1024;
      float* kvacc_b  = kvacc + (long)b * H_ * 64 * 256;
      _Float16* kvh_b = kvh   + (long)b * H_ * 64 * 256;
      // fourier q (bz=0, A=Pb_b, norms) + k (bz=1, A=Sb_b) in one launch;
      // K=192 split-f16 vs proj3T; M=65536 rows of [l*16+h][64]
      gemm_bt_k<128, 128, 2, 6, 1, _Float16><<<dim3(512, 1, 2), 256, 0, stream>>>(
          Pb + (long)bb * 4194304, proj3T, qpr, 192, 64, 192, 0,
          0, 8388608L, 0, 0, 0, 16777216L,
          normsB + (long)bb * 65536, nullptr, nullptr, nullptr, nullptr);
      // kv (split-K=16 over L with atomics) -> kvacc_b; cast to f16
      kv_k<<<dim3(16, KV_SPLIT), 256, 0, stream>>>(kpr, Vh_b, kvacc_b);
      cast_out_f16_k<<<1024, 256, 0, stream>>>(kvacc_b, kvh_b, 262144);
      // z = q'' @ kvT (batched over h), C -> Zb_b [L][1024]
      gemm_bt_k<128, 64, 0, 0, 0, _Float16><<<dim3(32, 1, 16), 256, 0, stream>>>(
          qpr, kvh_b, Zb_b, 256, 256, 256, 1024,
          0L, (long)L_ * 256, 0L, 16384L, 0L, 64L,
          nullptr, nullptr, nullptr, nullptr, nullptr);
    }
  }
  // out = z @ W_o (f32 out), M=16384
  gemm_bt_k<128, 128, 0, 0, 0, float><<<dim3(128, 8, 1), 256, 0, stream>>>(
      Zb, WoT, out, 1024, 1024, 1024, 1024, 0, 0, 0, 0, 0, 0,
      nullptr, nullptr, nullptr, nullptr, nullptr);
}